// Round 13
// baseline (792.748 us; speedup 1.0000x reference)
//
#include <hip/hip_runtime.h>

#define NSEQ 256
#define NRES 1024
#define CM   256
#define CC   32
#define CZ   128
#define EPS  1e-5f

typedef float f4v __attribute__((ext_vector_type(4)));
typedef __attribute__((ext_vector_type(8))) short short8;   // bf16x8 MFMA frag
typedef __attribute__((ext_vector_type(4))) float f32x4;    // MFMA acc
typedef unsigned int u32;

__device__ __forceinline__ float trunc_bf16(float f) {
    return __uint_as_float(__float_as_uint(f) & 0xffff0000u);
}
__device__ __forceinline__ u32 pk_bf16(float a, float b) {   // low=a, high=b
    return (__float_as_uint(b) & 0xffff0000u) | (__float_as_uint(a) >> 16);
}

// ===================== Kernel S: K1/K2 + B-fragment-arranged bf16x2 weights =====================
// (verbatim from round 8 — validated end-to-end)
__global__ void opm_setup(const float* __restrict__ nw,
                          const float* __restrict__ nb,
                          const float* __restrict__ w_ab,
                          const float* __restrict__ b_ab,
                          float* __restrict__ k12,
                          unsigned short* __restrict__ wb_su)
{
    __shared__ float wls[CM * CC];
    const int t = threadIdx.x;          // 256 threads, t == m
    const float nwm = nw[t];
    #pragma unroll
    for (int c = 0; c < CC; ++c)
        wls[t * CC + c] = nwm * w_ab[c * CM + t];
    __syncthreads();
    if (t < CC) {
        float k1 = 0.f, k2 = 0.f;
        for (int m = 0; m < CM; ++m) {
            k1 += wls[m * CC + t];
            k2 = fmaf(nb[m], w_ab[t * CM + m], k2);
        }
        k12[t]      = k1;
        k12[CC + t] = k2 + b_ab[t];
    }
    for (int e = t; e < 16384; e += 256) {
        const int j     = e & 7;
        const int l     = (e >> 3) & 63;
        const int split = (e >> 9) & 1;
        const int nt    = (e >> 10) & 1;
        const int kk    = e >> 11;
        const int m = (kk << 5) + ((l >> 4) << 3) + j;
        const int c = (nt << 4) + (l & 15);
        const float w  = wls[m * CC + c];
        const float w1 = trunc_bf16(w);
        const float v  = split ? (w - w1) : w;
        wb_su[e] = (unsigned short)(__float_as_uint(v) >> 16);
    }
}

// ===================== K1: LN + projection with DENSE sequential reads =====================
// Block = (s, 32-row r-slab): reads msa[s][r0:r0+32][:] = 32 KB CONTIGUOUS;
// every wave-instruction covers 1 KB contiguous (fill-kernel request shape).
// LDS tile xt[32][256] f32, 16-B slots XOR-swizzled (m4 ^= row&7) so the
// MFMA A-reads spread 8 quads (linear layout would be 16-way same-quad).
// Wave = (mt = w&1 row-tile, nt = w>>1 col-half): per kk: 2 ds_read_b128 ->
// in-lane bf16x2 convert (r8-validated) -> 3 MFMA; B-frags from global
// (L2-hot 32 KB), prefetched one kk ahead. Stats register-fed from the
// A-read values, reduced over lk via shfl(16/32), published via st LDS.
// P2: LN-fold -> a tile in LDS -> coalesced 128-B-segment writes to
// a_ws[r][s][c] (r-stride 32 KB).
__launch_bounds__(256, 4)
__global__ void opm_lnproj(const float* __restrict__ msa,
                           const u32*  __restrict__ wb_g,
                           const float* __restrict__ k12,
                           float* __restrict__ a_ws)
{
    __shared__ float xt[32 * 256];   // 32 KB x-tile; reused for a[32][32] in P2
    __shared__ float st[64];         // mu[0..31], rstd[32..63]

    const int tid = threadIdx.x;
    const int s   = blockIdx.x >> 5;            // 0..255
    const int r0  = (blockIdx.x & 31) << 5;     // 0..992
    const int w   = tid >> 6;                    // wave 0..3
    const int l   = tid & 63;
    const int lr  = l & 15;                      // A-row in tile / C-col
    const int lk  = l >> 4;                      // k-group 0..3
    const int mt  = w & 1;                       // row-tile 0..1
    const int nt  = w >> 1;                      // col-half 0..1

    const float* xb = msa + ((size_t)s * NRES + r0) * CM;

    // ---- stage: 8 float4/thread; instruction j covers 4 KB contiguous per block ----
    float4 pf[8];
    #pragma unroll
    for (int j = 0; j < 8; ++j)
        pf[j] = *(const float4*)(xb + (size_t)(((j << 8) + tid) << 2));
    #pragma unroll
    for (int j = 0; j < 8; ++j) {
        const int row = (j << 2) + w;            // = ((j*256+tid)>>6)
        *(float4*)&xt[(row << 8) + ((l ^ (row & 7)) << 2)] = pf[j];
    }
    __syncthreads();   // (A) tile visible

    // ---- MFMA: G[r-tile 16][c-half 16] over m=256, bf16x2 3-product ----
    f32x4 acc = (f32x4)0.f;
    float psum = 0.f, pssq = 0.f;
    const int arow = ((mt << 4) + lr) << 8;      // tile row base (floats)
    const int sw8  = lr & 7;

    f4v bs0 = *(const f4v*)&wb_g[(((0 + nt) << 1) + 0) * 256 + (l << 2)];
    f4v bs1 = *(const f4v*)&wb_g[(((0 + nt) << 1) + 1) * 256 + (l << 2)];

    #pragma unroll
    for (int kk = 0; kk < 8; ++kk) {
        f4v nb0, nb1;
        if (kk < 7) {   // prefetch next kk's B-frags (L2-resident)
            nb0 = *(const f4v*)&wb_g[((((kk + 1) << 1) + nt) << 1) * 256 + (l << 2)];
            nb1 = *(const f4v*)&wb_g[(((((kk + 1) << 1) + nt) << 1) + 1) * 256 + (l << 2)];
        }
        const int m4 = (kk << 3) + (lk << 1);
        const float4 pa = *(const float4*)&xt[arow + ((m4 ^ sw8) << 2)];
        const float4 pb = *(const float4*)&xt[arow + (((m4 + 1) ^ sw8) << 2)];
        psum += ((pa.x + pa.y) + (pa.z + pa.w)) + ((pb.x + pb.y) + (pb.z + pb.w));
        pssq  = fmaf(pa.x, pa.x, fmaf(pa.y, pa.y, fmaf(pa.z, pa.z, fmaf(pa.w, pa.w, pssq))));
        pssq  = fmaf(pb.x, pb.x, fmaf(pb.y, pb.y, fmaf(pb.z, pb.z, fmaf(pb.w, pb.w, pssq))));
        uint4 u1, u2;
        u1.x = pk_bf16(pa.x, pa.y); u1.y = pk_bf16(pa.z, pa.w);
        u1.z = pk_bf16(pb.x, pb.y); u1.w = pk_bf16(pb.z, pb.w);
        u2.x = pk_bf16(pa.x - trunc_bf16(pa.x), pa.y - trunc_bf16(pa.y));
        u2.y = pk_bf16(pa.z - trunc_bf16(pa.z), pa.w - trunc_bf16(pa.w));
        u2.z = pk_bf16(pb.x - trunc_bf16(pb.x), pb.y - trunc_bf16(pb.y));
        u2.w = pk_bf16(pb.z - trunc_bf16(pb.z), pb.w - trunc_bf16(pb.w));
        const short8 A1 = __builtin_bit_cast(short8, u1);
        const short8 A2 = __builtin_bit_cast(short8, u2);
        const short8 B0 = __builtin_bit_cast(short8, bs0);
        const short8 B1 = __builtin_bit_cast(short8, bs1);
        acc = __builtin_amdgcn_mfma_f32_16x16x32_bf16(A1, B0, acc, 0, 0, 0);
        acc = __builtin_amdgcn_mfma_f32_16x16x32_bf16(A1, B1, acc, 0, 0, 0);
        acc = __builtin_amdgcn_mfma_f32_16x16x32_bf16(A2, B0, acc, 0, 0, 0);
        if (kk < 7) { bs0 = nb0; bs1 = nb1; }
    }

    // ---- stats: reduce over the 4 lk-groups; nt==0 waves publish ----
    psum += __shfl_xor(psum, 16); psum += __shfl_xor(psum, 32);
    pssq += __shfl_xor(pssq, 16); pssq += __shfl_xor(pssq, 32);
    if (nt == 0 && l < 16) {
        const int R = (mt << 4) + lr;
        const float mu  = psum * (1.f / CM);
        const float var = pssq * (1.f / CM) - mu * mu;
        st[R]      = mu;
        st[32 + R] = 1.f / sqrtf(var + EPS);
    }
    __syncthreads();   // (B) all MFMA tile-reads done; stats visible

    // ---- P2: LN-fold -> a[32][32] in xt; coalesced writeout to a_ws[r][s][c] ----
    {
        const int c  = lr + (nt << 4);
        const float k1 = k12[c], k2 = k12[CC + c];
        #pragma unroll
        for (int rg = 0; rg < 4; ++rg) {
            const int R = (mt << 4) + (lk << 2) + rg;
            const float mu = st[R], rs = st[32 + R];
            xt[R * CC + c] = fmaf(rs, acc[rg] - mu * k1, k2);
        }
    }
    __syncthreads();   // (C) a tile complete
    {
        const int row = tid >> 3, c4 = tid & 7;
        const float4 v = *(const float4*)&xt[row * CC + (c4 << 2)];
        *(float4*)&a_ws[((size_t)(r0 + row) * NSEQ + s) * CC + (c4 << 2)] = v;
    }
}

// ===================== K2: o = A^T A / NSEQ and pre[z], per residue =====================
// Block = r: reads a_ws[r][:][:] = 32 KB CONTIGUOUS (1 KB per wave-instr),
// stages into the r11 XOR-swizzled a-layout; P3/P4 verbatim from round 11.
__launch_bounds__(256, 3)
__global__ void opm_outer(const float* __restrict__ a_ws,
                          const float* __restrict__ w_out,
                          const float* __restrict__ b_out,
                          float* __restrict__ pre_out)
{
    __shared__ float aB[NSEQ * CC];    // 32 KB, XOR-swizzled f4 slots
    __shared__ float scr[4352];        // 17 KB: P3 partials/o + pre_part

    const int tid = threadIdx.x;
    const int r   = blockIdx.x;
    const int w   = tid >> 6;

    const float* ab = a_ws + (size_t)r * NSEQ * CC;
    #pragma unroll
    for (int k = 0; k < 8; ++k) {
        const int f  = (k << 8) + tid;       // float4 index
        const int s_ = f >> 3;
        const int c4 = f & 7;
        const float4 v = *(const float4*)(ab + ((size_t)f << 2));
        *(float4*)&aB[s_ * CC + ((c4 ^ (s_ & 7)) << 2)] = v;
    }
    __syncthreads();

    // ---------------- P3: o = A^T A / NSEQ, split-K(4) x 4x4 tiles ----------------
    const int grp = w;                 // s-slice 64*grp .. +63
    const int xs_ = (tid >> 3) & 7;    // row f4-slot
    const int ys_ = tid & 7;           // col f4-slot
    float4 pr0 = {0,0,0,0}, pr1 = {0,0,0,0}, pr2 = {0,0,0,0}, pr3 = {0,0,0,0};
    #pragma unroll 4
    for (int si = 0; si < 64; ++si) {
        const int s  = (grp << 6) + si;
        const int sw = s & 7;
        const float4 ax = *(const float4*)&aB[s * CC + ((xs_ ^ sw) << 2)];
        const float4 ay = *(const float4*)&aB[s * CC + ((ys_ ^ sw) << 2)];
        pr0.x = fmaf(ax.x, ay.x, pr0.x); pr0.y = fmaf(ax.x, ay.y, pr0.y);
        pr0.z = fmaf(ax.x, ay.z, pr0.z); pr0.w = fmaf(ax.x, ay.w, pr0.w);
        pr1.x = fmaf(ax.y, ay.x, pr1.x); pr1.y = fmaf(ax.y, ay.y, pr1.y);
        pr1.z = fmaf(ax.y, ay.z, pr1.z); pr1.w = fmaf(ax.y, ay.w, pr1.w);
        pr2.x = fmaf(ax.z, ay.x, pr2.x); pr2.y = fmaf(ax.z, ay.y, pr2.y);
        pr2.z = fmaf(ax.z, ay.z, pr2.z); pr2.w = fmaf(ax.z, ay.w, pr2.w);
        pr3.x = fmaf(ax.w, ay.x, pr3.x); pr3.y = fmaf(ax.w, ay.y, pr3.y);
        pr3.z = fmaf(ax.w, ay.z, pr3.z); pr3.w = fmaf(ax.w, ay.w, pr3.w);
    }
    {
        float* pb = &scr[(grp << 10) + ((xs_ << 2) * CC) + (ys_ << 2)];
        *(float4*)&pb[0 * CC] = pr0;
        *(float4*)&pb[1 * CC] = pr1;
        *(float4*)&pb[2 * CC] = pr2;
        *(float4*)&pb[3 * CC] = pr3;
    }
    __syncthreads();   // partials visible
    {
        const float inv_s = 1.f / NSEQ;
        float4 a4 = *(const float4*)&scr[(tid << 2)];
        const float4 b1 = *(const float4*)&scr[1024 + (tid << 2)];
        const float4 b2 = *(const float4*)&scr[2048 + (tid << 2)];
        const float4 b3 = *(const float4*)&scr[3072 + (tid << 2)];
        a4.x = (a4.x + b1.x + b2.x + b3.x) * inv_s;
        a4.y = (a4.y + b1.y + b2.y + b3.y) * inv_s;
        a4.z = (a4.z + b1.z + b2.z + b3.z) * inv_s;
        a4.w = (a4.w + b1.w + b2.w + b3.w) * inv_s;
        *(float4*)&scr[tid << 2] = a4;
    }
    __syncthreads();   // o visible

    // ---------------- P4: pre[z] = o . w_out[z] + b_out[z] ----------------
    {
        const int z    = tid & 127;
        const int half = tid >> 7;
        const float* wrow = w_out + (size_t)z * (CC * CC) + half * 512;
        const float* op   = &scr[half * 512];
        float po = 0.f;
        #pragma unroll 8
        for (int k = 0; k < 512; k += 4) {
            const float4 o4 = *(const float4*)&op[k];
            const float4 w4 = *(const float4*)&wrow[k];
            po = fmaf(o4.x, w4.x, fmaf(o4.y, w4.y, fmaf(o4.z, w4.z, fmaf(o4.w, w4.w, po))));
        }
        scr[4096 + (half << 7) + z] = po;
    }
    __syncthreads();
    if (tid < CZ)
        pre_out[(size_t)r * CZ + tid] = scr[4096 + tid] + scr[4096 + CZ + tid] + b_out[tid];
}

// ===================== Kernel B: broadcast pre over 1024 rows =====================
__launch_bounds__(256, 8)
__global__ void opm_bcast(const float* __restrict__ pre,
                          float* __restrict__ out)
{
    const int bid = blockIdx.x;
    const int r   = bid >> 3;                 // 0..1023
    const int jb  = bid & 7;                  // 128-row slab within the r-plane
    const int z4  = threadIdx.x & 31;         // which float4 of the 128-float row
    const int jo  = threadIdx.x >> 5;         // 0..7

    const f4v pv = *((const f4v*)(pre + (size_t)r * CZ) + z4);
    f4v* outp = (f4v*)out + ((size_t)r * NRES + (size_t)jb * 128) * (CZ / 4);
    for (int j0 = 0; j0 < 128; j0 += 8)
        __builtin_nontemporal_store(pv, &outp[(size_t)(j0 + jo) * (CZ / 4) + z4]);
}

extern "C" void kernel_launch(void* const* d_in, const int* in_sizes, int n_in,
                              void* d_out, int out_size, void* d_ws, size_t ws_size,
                              hipStream_t stream) {
    const float* msa   = (const float*)d_in[0];
    const float* nw    = (const float*)d_in[1];
    const float* nb    = (const float*)d_in[2];
    const float* w_ab  = (const float*)d_in[3];
    const float* b_ab  = (const float*)d_in[4];
    const float* w_out = (const float*)d_in[5];
    const float* b_out = (const float*)d_in[6];
    float* out = (float*)d_out;

    float* pre = (float*)d_ws;                           // [0, 131072) floats
    float* k12 = pre + (size_t)NRES * CZ;                // [131072, 131136)
    unsigned short* wb_su = (unsigned short*)(k12 + 64); // 16384 bf16 (32 KB)
    float* a_ws = (float*)(wb_su + 16384);               // 32 MB: a[r][s][c]

    opm_setup<<<1, 256, 0, stream>>>(nw, nb, w_ab, b_ab, k12, wb_su);
    opm_lnproj<<<NSEQ * 32, 256, 0, stream>>>(msa, (const u32*)wb_su, k12, a_ws);
    opm_outer<<<NRES, 256, 0, stream>>>(a_ws, w_out, b_out, pre);
    opm_bcast<<<NRES * 8, 256, 0, stream>>>(pre, out);
}